// Round 1
// baseline (883.853 us; speedup 1.0000x reference)
//
#include <hip/hip_runtime.h>
#include <hip/hip_bf16.h>

// Shapes: prototypes [64,1024] f32, hidden_states [4,1024,1024] f32,
// logits [4,1,1024,32000] f32. Output = logits with per-row top-20 set to
// -100.0f, only for batches whose mean prototype cosine sim > 0.
//
// ws layout: [0, 16384)  : emb accumulator, 4*1024 f32 (zeroed each call)
//            [16384, +16): flags, 4 ints

#define ROW_ELEMS 32000
#define ROW_VEC4  8000
#define CAND_CAP  2048
#define CAND_THRESH 2.0f
#define TOPK 20

// ---------------------------------------------------------------- emb ------
// emb[b][d] = sum_p hs[b][p][d]  (1/1024 scale dropped: cancels in normalize)
__global__ __launch_bounds__(256) void emb_kernel(const float* __restrict__ hs,
                                                  float* __restrict__ emb) {
  const int tid = threadIdx.x;
  const int pc = blockIdx.x & 15;          // 16 position-chunks of 64
  const int dc = (blockIdx.x >> 4) & 3;    // 4 dim-chunks of 256
  const int b  = blockIdx.x >> 6;          // 4 batches
  const int d  = dc * 256 + tid;
  const float* p = hs + (size_t)b * 1048576 + (size_t)(pc * 64) * 1024 + d;
  float s = 0.f;
#pragma unroll 8
  for (int i = 0; i < 64; ++i) s += p[(size_t)i * 1024];
  atomicAdd(&emb[b * 1024 + d], s);
}

// ---------------------------------------------------------------- sim ------
__global__ __launch_bounds__(256) void sim_kernel(const float* __restrict__ proto,
                                                  const float* __restrict__ emb,
                                                  int* __restrict__ flags) {
  const int tid = threadIdx.x;
  const int wid = tid >> 6, lane = tid & 63;
  __shared__ float prinv_s[64];   // 1 / max(||proto_j||, eps)
  __shared__ float enorm_s[4];    // max(||emb_b||, eps)
  __shared__ float pbar_s[1024];

  // prototype norms: wave wid handles rows wid*16 .. wid*16+15
  for (int rr = 0; rr < 16; ++rr) {
    const int r = wid * 16 + rr;
    float ss = 0.f;
    for (int i = 0; i < 16; ++i) {
      float x = proto[r * 1024 + lane + i * 64];
      ss += x * x;
    }
    for (int off = 32; off; off >>= 1) ss += __shfl_xor(ss, off);
    if (lane == 0) prinv_s[r] = 1.0f / fmaxf(sqrtf(ss), 1e-8f);
  }
  // emb norms: wave wid handles batch wid
  {
    float ss = 0.f;
    for (int i = 0; i < 16; ++i) {
      float x = emb[wid * 1024 + lane + i * 64];
      ss += x * x;
    }
    for (int off = 32; off; off >>= 1) ss += __shfl_xor(ss, off);
    if (lane == 0) enorm_s[wid] = fmaxf(sqrtf(ss), 1e-8f);
  }
  __syncthreads();
  // pbar[d] = sum_j proto[j][d] / ||proto_j||   (coalesced over d)
  for (int k = 0; k < 4; ++k) {
    const int d = k * 256 + tid;
    float s = 0.f;
    for (int j = 0; j < 64; ++j) s += proto[j * 1024 + d] * prinv_s[j];
    pbar_s[d] = s;
  }
  __syncthreads();
  // sim[b] = (emb[b] . pbar) / (64 * ||emb_b||)   → flag = sim > 0
  {
    float s = 0.f;
    for (int i = 0; i < 16; ++i) {
      const int d = lane + i * 64;
      s += emb[wid * 1024 + d] * pbar_s[d];
    }
    for (int off = 32; off; off >>= 1) s += __shfl_xor(s, off);
    if (lane == 0) flags[wid] = ((s / 64.0f / enorm_s[wid]) > 0.0f) ? 1 : 0;
  }
}

// ----------------------------------------------------------- suppress ------
// One block per row. Copy the row (float4) while collecting candidates
// > CAND_THRESH into LDS; then extract the exact top-20 by key
// (value desc, index asc — matches lax.top_k ties) and scatter -100.0f.
__global__ __launch_bounds__(256) void suppress_kernel(const float* __restrict__ logits,
                                                       float* __restrict__ out,
                                                       const int* __restrict__ flags) {
  const int row = blockIdx.x;              // 0..4095
  const int tid = threadIdx.x;
  const size_t base = (size_t)row * ROW_ELEMS;
  const float4* __restrict__ src = (const float4*)(logits + base);
  float4* __restrict__ dst = (float4*)(out + base);
  const bool sup = flags[row >> 10] != 0;

  if (!sup) {
#pragma unroll 4
    for (int i = tid; i < ROW_VEC4; i += 256) dst[i] = src[i];
    return;
  }

  __shared__ unsigned long long keys[CAND_CAP];
  __shared__ unsigned long long wmax[4];
  __shared__ int cnt;
  if (tid == 0) cnt = 0;
  __syncthreads();

  // streaming copy + candidate collection
  for (int i = tid; i < ROW_VEC4; i += 256) {
    float4 v = src[i];
    dst[i] = v;
    const float vals[4] = {v.x, v.y, v.z, v.w};
#pragma unroll
    for (int c = 0; c < 4; ++c) {
      if (vals[c] > CAND_THRESH) {
        int p = atomicAdd(&cnt, 1);
        if (p < CAND_CAP) {
          // candidates are > 2.0 → positive → ordered bits = bits | signbit
          unsigned int u = __float_as_uint(vals[c]) | 0x80000000u;
          keys[p] = ((unsigned long long)u << 32) |
                    (unsigned int)(~(unsigned int)(4 * i + c));
        }
      }
    }
  }
  __syncthreads();
  const int n = cnt;

  if (n >= TOPK && n <= CAND_CAP) {
    // fast path: 20 rounds of block-argmax over the LDS candidate list
    for (int r = 0; r < TOPK; ++r) {
      unsigned long long local = 0ull;
      int slot = -1;
      for (int j = tid; j < n; j += 256) {
        unsigned long long k = keys[j];
        if (k > local) { local = k; slot = j; }
      }
      unsigned long long red = local;
      for (int off = 32; off; off >>= 1) {
        unsigned long long o = __shfl_xor(red, off);
        if (o > red) red = o;
      }
      if ((tid & 63) == 0) wmax[tid >> 6] = red;
      __syncthreads();
      unsigned long long winner = wmax[0];
      for (int w = 1; w < 4; ++w) if (wmax[w] > winner) winner = wmax[w];
      if (slot >= 0 && local == winner) keys[slot] = 0ull;  // unique owner
      if (tid == 0) {
        unsigned int idx = ~(unsigned int)winner;
        out[base + idx] = -100.0f;
      }
      __syncthreads();
    }
  } else {
    // slow path (distribution-independent): 20 exact argmax scans of the row
    unsigned long long prev = ~0ull;
    for (int r = 0; r < TOPK; ++r) {
      unsigned long long local = 0ull;
      for (int e = tid; e < ROW_ELEMS; e += 256) {
        float x = logits[base + e];
        unsigned int u = __float_as_uint(x);
        u = ((int)u < 0) ? ~u : (u | 0x80000000u);
        unsigned long long k = ((unsigned long long)u << 32) |
                               (unsigned int)(~(unsigned int)e);
        if (k < prev && k > local) local = k;
      }
      for (int off = 32; off; off >>= 1) {
        unsigned long long o = __shfl_xor(local, off);
        if (o > local) local = o;
      }
      if ((tid & 63) == 0) wmax[tid >> 6] = local;
      __syncthreads();
      unsigned long long winner = wmax[0];
      for (int w = 1; w < 4; ++w) if (wmax[w] > winner) winner = wmax[w];
      if (tid == 0) {
        unsigned int idx = ~(unsigned int)winner;
        out[base + idx] = -100.0f;
      }
      prev = winner;
      __syncthreads();
    }
  }
}

// -------------------------------------------------------------- launch -----
extern "C" void kernel_launch(void* const* d_in, const int* in_sizes, int n_in,
                              void* d_out, int out_size, void* d_ws, size_t ws_size,
                              hipStream_t stream) {
  const float* proto  = (const float*)d_in[0];   // [64,1024]
  const float* hs     = (const float*)d_in[1];   // [4,1024,1024]
  const float* logits = (const float*)d_in[2];   // [4,1,1024,32000]
  float* out = (float*)d_out;

  float* emb  = (float*)d_ws;
  int*   flags = (int*)((char*)d_ws + 4096 * sizeof(float));

  hipMemsetAsync(d_ws, 0, 4096 * sizeof(float), stream);
  emb_kernel<<<256, 256, 0, stream>>>(hs, emb);
  sim_kernel<<<1, 256, 0, stream>>>(proto, emb, flags);
  suppress_kernel<<<4096, 256, 0, stream>>>(logits, out, flags);
}